// Round 5
// baseline (134.999 us; speedup 1.0000x reference)
//
#include <hip/hip_runtime.h>
#include <math.h>

#define B_SZ 2
#define N_PRED 256
#define M_GT 32
#define L_TOK 16
#define V_VOCAB 32000
#define P_POS 15            // L_TOK-1 predicted positions
#define NROW 960            // B*M*P = 2*32*15 caption rows
#define NQ 4                // quarters per row
#define Q4 2000             // float4s per quarter (32000/4/4)

__device__ __forceinline__ float giou_f(float4 b1, float4 b2) {
    float ax1 = fminf(b1.x, b1.z), ay1 = fminf(b1.y, b1.w);
    float ax2 = fmaxf(b1.x, b1.z), ay2 = fmaxf(b1.y, b1.w);
    float bx1 = fminf(b2.x, b2.z), by1 = fminf(b2.y, b2.w);
    float bx2 = fmaxf(b2.x, b2.z), by2 = fmaxf(b2.y, b2.w);
    float xi1 = fmaxf(ax1, bx1), yi1 = fmaxf(ay1, by1);
    float xi2 = fminf(ax2, bx2), yi2 = fminf(ay2, by2);
    float inter = fmaxf(xi2 - xi1, 0.f) * fmaxf(yi2 - yi1, 0.f);
    float a1 = (ax2 - ax1) * (ay2 - ay1);
    float a2 = (bx2 - bx1) * (by2 - by1);
    float uni = a1 + a2 - inter;
    float iou = inter / (uni + 1e-7f);
    float xe1 = fminf(ax1, bx1), ye1 = fminf(ay1, by1);
    float xe2 = fmaxf(ax2, bx2), ye2 = fmaxf(ay2, by2);
    float enc = (xe2 - xe1) * (ye2 - ye1);
    return iou - (enc - uni) / (enc + 1e-7f);
}

// One DPP min-scan step on the (khi,klo) u64 key. For lanes with no source
// (row_shr edge / masked row) update_dpp returns old = 0xFFFFFFFF -> key
// ~0ULL -> no-op in the min. Pure VALU (no LDS latency).
#define DPP_STEP(ctrl, rmask)                                              \
    {                                                                      \
        unsigned nlo = (unsigned)__builtin_amdgcn_update_dpp(              \
            (int)0xFFFFFFFF, (int)klo, (ctrl), (rmask), 0xF, false);       \
        unsigned nhi = (unsigned)__builtin_amdgcn_update_dpp(              \
            (int)0xFFFFFFFF, (int)khi, (ctrl), (rmask), 0xF, false);       \
        if (nhi < khi || (nhi == khi && nlo < klo)) { khi = nhi; klo = nlo; } \
    }

// One block of 256 threads per sample.
// Phase 1 (4 waves): each thread computes one cost row (32 GIoU), stores it
//   + per-row best to LDS; partial match-independent BCE reduce.
// Phase 2 (wave 0 only): 4 rows/lane in registers; 32 greedy iterations.
//   Global argmin via u64 key (cost_bits<<13 | flat; costs>0 so float bit
//   order == value order; min == lexicographic (value, flat) == jnp.argmin
//   first-occurrence) reduced by a 6-step DPP min-scan (row_shr 1/2/4/8 +
//   row_bcast15/31) -> lane 63 -> readlane broadcast. No LDS/barriers in loop.
__global__ __launch_bounds__(256, 1) void match_bbox_obj_kernel(
    const float* __restrict__ pred_boxes, const float* __restrict__ pred_obj,
    const float* __restrict__ gt_boxes,
    int* __restrict__ pis, int* __restrict__ gjs,
    float* __restrict__ bbox_out, float* __restrict__ obj_out)
{
    const int b   = blockIdx.x;
    const int tid = threadIdx.x;          // = pred row index in phase 1
    const int wv  = tid >> 6;
    const int ln  = tid & 63;

    __shared__ float  costS[N_PRED][33];  // +1 pad: bank-conflict-free col reads
    __shared__ float  rbv[N_PRED];
    __shared__ int    rbj[N_PRED];
    __shared__ float  poS[N_PRED];
    __shared__ float4 pbS[N_PRED];
    __shared__ float4 gbS[M_GT];
    __shared__ float  obase[4];

    if (tid < M_GT) gbS[tid] = ((const float4*)gt_boxes)[b * M_GT + tid];
    const float4 p  = ((const float4*)pred_boxes)[b * N_PRED + tid];
    const float  po = pred_obj[b * N_PRED + tid];
    pbS[tid] = p;
    poS[tid] = po;
    __syncthreads();

    // ---- phase 1: cost row + per-row best ----
    const float objc = 1.f - 1.f / (1.f + __expf(-po));
    {
        float bv = INFINITY; int bj = 0;
#pragma unroll
        for (int j = 0; j < M_GT; ++j) {
            float4 g = gbS[j];
            float l1 = fabsf(p.x - g.x) + fabsf(p.y - g.y) +
                       fabsf(p.z - g.z) + fabsf(p.w - g.w);
            float c = l1 + (1.f - giou_f(p, g)) + objc;
            costS[tid][j] = c;
            if (c < bv) { bv = c; bj = j; }   // strict < -> smallest j on tie
        }
        rbv[tid] = bv; rbj[tid] = bj;
    }
    // match-independent BCE part: max(po,0) + log1p(exp(-|po|))
    {
        float ob = fmaxf(po, 0.f) + log1pf(__expf(-fabsf(po)));
        for (int off = 32; off > 0; off >>= 1) ob += __shfl_xor(ob, off);
        if (ln == 0) obase[wv] = ob;
    }
    __syncthreads();

    if (wv != 0) return;   // wave 0 runs the serial greedy alone

    // ---- phase 2: registers for wave 0's 4 rows/lane ----
    float cr[4][M_GT];
    float bestv[4];
    int   bestj[4];
#pragma unroll
    for (int q = 0; q < 4; ++q) {
        const int i = ln + 64 * q;
#pragma unroll
        for (int j = 0; j < M_GT; ++j) cr[q][j] = costS[i][j];
        bestv[q] = rbv[i]; bestj[q] = rbj[i];
    }

    unsigned colUsed = 0;
    int rowUsed = 0;            // bitmask over q
    int my_pi = 0, my_gj = 0;   // lane t holds match t (t < 32)

    for (int t = 0; t < M_GT; ++t) {
        // per-lane candidate key over its unused rows
        unsigned klo = 0xFFFFFFFFu, khi = 0xFFFFFFFFu;
#pragma unroll
        for (int q = 0; q < 4; ++q) {
            if (!((rowUsed >> q) & 1)) {
                unsigned cb = __float_as_uint(bestv[q]);
                unsigned h = cb >> 19;
                unsigned l = (cb << 13) | (unsigned)((ln + 64 * q) * M_GT + bestj[q]);
                if (h < khi || (h == khi && l < klo)) { khi = h; klo = l; }
            }
        }
        // 6-step DPP inclusive min-scan -> lane 63 has the global min
        DPP_STEP(0x111, 0xF);   // row_shr:1
        DPP_STEP(0x112, 0xF);   // row_shr:2
        DPP_STEP(0x114, 0xF);   // row_shr:4
        DPP_STEP(0x118, 0xF);   // row_shr:8
        DPP_STEP(0x142, 0xA);   // row_bcast15 -> rows 1,3
        DPP_STEP(0x143, 0xC);   // row_bcast31 -> rows 2,3
        const unsigned glo = (unsigned)__builtin_amdgcn_readlane((int)klo, 63);

        const int flat = (int)(glo & 0x1FFFu);
        const int wi = flat >> 5;
        const int wj = flat & 31;
        if (ln == t) { my_pi = wi; my_gj = wj; }
        colUsed |= 1u << wj;
        if ((wi & 63) == ln) rowUsed |= 1 << (wi >> 6);
        // rescan rows whose cached best column was just consumed (registers)
#pragma unroll
        for (int q = 0; q < 4; ++q) {
            if (!((rowUsed >> q) & 1) && bestj[q] == wj) {
                float bv = INFINITY; int bj = 0;
#pragma unroll
                for (int j = 0; j < M_GT; ++j) {
                    float c = ((colUsed >> j) & 1) ? INFINITY : cr[q][j];
                    if (c < bv) { bv = c; bj = j; }
                }
                bestv[q] = bv; bestj[q] = bj;
            }
        }
    }

    if (ln < M_GT) {
        pis[b * M_GT + ln] = my_pi;
        gjs[b * M_GT + ln] = my_gj;
    }

    // bbox loss over matched pairs + matched-po sum
    float l1sum = 0.f, gsum = 0.f, mpo = 0.f;
    if (ln < M_GT) {
        float4 mp = pbS[my_pi];
        float4 mg = gbS[my_gj];
        l1sum = fabsf(mp.x - mg.x) + fabsf(mp.y - mg.y) +
                fabsf(mp.z - mg.z) + fabsf(mp.w - mg.w);
        gsum = 1.f - giou_f(mp, mg);
        mpo  = poS[my_pi];
    }
    for (int off = 32; off > 0; off >>= 1) {
        l1sum += __shfl_xor(l1sum, off);
        gsum  += __shfl_xor(gsum,  off);
        mpo   += __shfl_xor(mpo,   off);
    }
    if (ln == 0) {
        float l1_loss   = l1sum / 128.f;                       // mean over (32,4)
        float giou_loss = fminf(fmaxf(gsum / 32.f, 0.f), 2.f); // clip [0,2]
        bbox_out[b] = fmaxf(l1_loss + giou_loss, 0.f);
        float ot = obase[0] + obase[1] + obase[2] + obase[3] - mpo;
        obj_out[b]  = fmaxf(ot / 256.f, 0.f);
    }
}

// One block per (row r, quarter qq): bid = r*4+qq, r = b*480 + k*15 + p.
// Partial online softmax over 8000 contiguous floats (32 KB), float4 loads;
// writes partial (m, s). qq==0 block also grabs the target logit.
__global__ __launch_bounds__(256) void caption_lse_kernel(
    const float* __restrict__ cl, const int* __restrict__ gt_tokens,
    const int* __restrict__ pis, const int* __restrict__ gjs,
    float* __restrict__ pm, float* __restrict__ ps, float* __restrict__ tl)
{
    const int bid = blockIdx.x;
    const int qq  = bid & 3;
    const int r   = bid >> 2;
    const int b   = r / (M_GT * P_POS);
    const int rem = r % (M_GT * P_POS);
    const int k   = rem / P_POS;
    const int p   = rem % P_POS;
    const int tid = threadIdx.x;

    const int n = pis[b * M_GT + k];
    const float* row = cl + ((size_t)(b * N_PRED + n) * L_TOK + p) * V_VOCAB;
    const float4* row4 = (const float4*)row;

    float m = -INFINITY, s = 0.f;
    const int end = (qq + 1) * Q4;
#pragma unroll 4
    for (int idx = qq * Q4 + tid; idx < end; idx += 256) {
        float4 v = row4[idx];
        float m4 = fmaxf(fmaxf(v.x, v.y), fmaxf(v.z, v.w));
        float mn = fmaxf(m, m4);
        s = s * __expf(m - mn) +
            __expf(v.x - mn) + __expf(v.y - mn) +
            __expf(v.z - mn) + __expf(v.w - mn);
        m = mn;
    }

    __shared__ float sm[256], ss[256];
    sm[tid] = m; ss[tid] = s;
    __syncthreads();
    for (int off = 128; off > 0; off >>= 1) {
        if (tid < off) {
            float m1 = sm[tid], s1 = ss[tid];
            float m2 = sm[tid + off], s2 = ss[tid + off];
            float mm = fmaxf(m1, m2);
            ss[tid] = s1 * __expf(m1 - mm) + s2 * __expf(m2 - mm);
            sm[tid] = mm;
        }
        __syncthreads();
    }
    if (tid == 0) {
        pm[bid] = sm[0];
        ps[bid] = ss[0];
        if (qq == 0) {
            const int gj  = gjs[b * M_GT + k];
            const int tgt = gt_tokens[(b * M_GT + gj) * L_TOK + (p + 1)];
            tl[r] = row[tgt];
        }
    }
}

// Merge 4 partials per row, per-match CE mean, clip/mean/weights -> out[4]
__global__ __launch_bounds__(64) void finalize_kernel(
    const float* __restrict__ pm, const float* __restrict__ ps,
    const float* __restrict__ tl,
    const float* __restrict__ bbox, const float* __restrict__ obj,
    float* __restrict__ out)
{
    const int l = threadIdx.x;      // l = b*32 + k; r = l*15 + p
    float sum = 0.f;
#pragma unroll
    for (int p = 0; p < P_POS; ++p) {
        int r = l * P_POS + p;
        float mm = fmaxf(fmaxf(pm[4*r], pm[4*r+1]), fmaxf(pm[4*r+2], pm[4*r+3]));
        float s  = ps[4*r]   * __expf(pm[4*r]   - mm) +
                   ps[4*r+1] * __expf(pm[4*r+1] - mm) +
                   ps[4*r+2] * __expf(pm[4*r+2] - mm) +
                   ps[4*r+3] * __expf(pm[4*r+3] - mm);
        sum += mm + __logf(s) - tl[r];
    }
    float cek = fmaxf(sum / (float)P_POS, 0.f);   // clip(ce,0) per match
    for (int off = 16; off > 0; off >>= 1) cek += __shfl_xor(cek, off);
    float cap_b = fmaxf(cek / (float)M_GT, 0.f);  // clip(mean,0) per sample
    float cap0 = __shfl(cap_b, 0);
    float cap1 = __shfl(cap_b, 32);
    if (l == 0) {
        float bb0 = bbox[0], bb1 = bbox[1];
        float ob0 = obj[0],  ob1 = obj[1];
        float per0 = 5.f * bb0 + 0.1f * cap0 + ob0;
        float per1 = 5.f * bb1 + 0.1f * cap1 + ob1;
        out[0] = fmaxf(0.5f * (per0 + per1), 0.f);
        out[1] = 5.f  * 0.5f * (bb0 + bb1);
        out[2] = 0.1f * 0.5f * (cap0 + cap1);
        out[3] = 0.5f * (ob0 + ob1);
    }
}

extern "C" void kernel_launch(void* const* d_in, const int* in_sizes, int n_in,
                              void* d_out, int out_size, void* d_ws, size_t ws_size,
                              hipStream_t stream) {
    const float* pred_boxes = (const float*)d_in[0];   // (2,256,4)
    const float* pred_obj   = (const float*)d_in[1];   // (2,256)
    const float* cap_logits = (const float*)d_in[2];   // (2,256,16,32000)
    const float* gt_boxes   = (const float*)d_in[3];   // (2,32,4)
    const int*   gt_tokens  = (const int*)d_in[4];     // (2,32,16) int32
    float* out = (float*)d_out;                        // (4,)

    int*   pis  = (int*)d_ws;                  // 64 ints
    int*   gjs  = pis + B_SZ * M_GT;           // 64 ints
    float* bbox = (float*)(gjs + B_SZ * M_GT); // 2 floats
    float* obj  = bbox + B_SZ;                 // 2 floats
    float* pm   = obj + B_SZ;                  // 3840 floats (960 rows x 4)
    float* ps   = pm + NQ * NROW;              // 3840 floats
    float* tl   = ps + NQ * NROW;              // 960 floats

    match_bbox_obj_kernel<<<B_SZ, 256, 0, stream>>>(
        pred_boxes, pred_obj, gt_boxes, pis, gjs, bbox, obj);
    caption_lse_kernel<<<NQ * NROW, 256, 0, stream>>>(
        cap_logits, gt_tokens, pis, gjs, pm, ps, tl);
    finalize_kernel<<<1, 64, 0, stream>>>(pm, ps, tl, bbox, obj, out);
}

// Round 6
// 83.750 us; speedup vs baseline: 1.6119x; 1.6119x over previous
//
#include <hip/hip_runtime.h>
#include <math.h>

#define B_SZ 2
#define N_PRED 256
#define M_GT 32
#define L_TOK 16
#define V_VOCAB 32000
#define P_POS 15            // L_TOK-1 predicted positions
#define NROW 960            // B*M*P = 2*32*15 caption rows
#define HALF4 4000          // float4s per half-row (32000/4/2)

__device__ __forceinline__ float giou_f(float4 b1, float4 b2) {
    float ax1 = fminf(b1.x, b1.z), ay1 = fminf(b1.y, b1.w);
    float ax2 = fmaxf(b1.x, b1.z), ay2 = fmaxf(b1.y, b1.w);
    float bx1 = fminf(b2.x, b2.z), by1 = fminf(b2.y, b2.w);
    float bx2 = fmaxf(b2.x, b2.z), by2 = fmaxf(b2.y, b2.w);
    float xi1 = fmaxf(ax1, bx1), yi1 = fmaxf(ay1, by1);
    float xi2 = fminf(ax2, bx2), yi2 = fminf(ay2, by2);
    float inter = fmaxf(xi2 - xi1, 0.f) * fmaxf(yi2 - yi1, 0.f);
    float a1 = (ax2 - ax1) * (ay2 - ay1);
    float a2 = (bx2 - bx1) * (by2 - by1);
    float uni = a1 + a2 - inter;
    float iou = inter / (uni + 1e-7f);
    float xe1 = fminf(ax1, bx1), ye1 = fminf(ay1, by1);
    float xe2 = fmaxf(ax2, bx2), ye2 = fmaxf(ay2, by2);
    float enc = (xe2 - xe1) * (ye2 - ye1);
    return iou - (enc - uni) / (enc + 1e-7f);
}

// ===== R4-proven match kernel (unchanged) =====
// 256 threads (4 waves) per sample; thread tid owns pred row tid.
// Cost row cr[32] lives in registers. Greedy iteration: per-thread cached
// best packed into u64 key (cost_bits<<13 | flat_idx; costs>0 so bit order
// == float order; min over key == lexicographic (value, flat) == jnp.argmin
// first-occurrence), 6-step intra-wave shuffle min, 4-entry LDS combine.
__global__ __launch_bounds__(256) void match_bbox_obj_kernel(
    const float* __restrict__ pred_boxes, const float* __restrict__ pred_obj,
    const float* __restrict__ gt_boxes,
    int* __restrict__ pis, int* __restrict__ gjs,
    float* __restrict__ bbox_out, float* __restrict__ obj_out)
{
    const int b   = blockIdx.x;
    const int tid = threadIdx.x;          // = pred row index
    const int wv  = tid >> 6;
    const int ln  = tid & 63;

    __shared__ float4 gbS[M_GT];
    __shared__ float4 pbS[N_PRED];
    __shared__ unsigned long long wkey[4];
    __shared__ float wosum[4];

    if (tid < M_GT) gbS[tid] = ((const float4*)gt_boxes)[b * M_GT + tid];

    const float4 p  = ((const float4*)pred_boxes)[b * N_PRED + tid];
    const float  po = pred_obj[b * N_PRED + tid];
    pbS[tid] = p;
    __syncthreads();

    const float objc = 1.f - 1.f / (1.f + __expf(-po));
    float cr[M_GT];
    float bestv = INFINITY; int bestj = 0;
#pragma unroll
    for (int j = 0; j < M_GT; ++j) {
        float4 g = gbS[j];
        float l1 = fabsf(p.x - g.x) + fabsf(p.y - g.y) +
                   fabsf(p.z - g.z) + fabsf(p.w - g.w);
        float c = l1 + (1.f - giou_f(p, g)) + objc;
        cr[j] = c;
        if (c < bestv) { bestv = c; bestj = j; }  // strict < -> smallest j
    }

    unsigned colUsed = 0;
    bool rowUsed = false;
    int my_pi = 0, my_gj = 0;   // thread t (t<32) records match t

    for (int t = 0; t < M_GT; ++t) {
        unsigned long long k = rowUsed ? ~0ULL :
            (((unsigned long long)__float_as_uint(bestv) << 13) |
             (unsigned)(tid * M_GT + bestj));
        // intra-wave u64 min
        for (int off = 32; off > 0; off >>= 1) {
            unsigned long long ko = __shfl_xor(k, off);
            if (ko < k) k = ko;
        }
        if (ln == 0) wkey[wv] = k;
        __syncthreads();
        unsigned long long g0 = wkey[0] < wkey[1] ? wkey[0] : wkey[1];
        unsigned long long g1 = wkey[2] < wkey[3] ? wkey[2] : wkey[3];
        unsigned long long g  = g0 < g1 ? g0 : g1;
        const int flat = (int)(g & 0x1FFFu);
        const int wi = flat >> 5;
        const int wj = flat & 31;
        if (tid == t)  { my_pi = wi; my_gj = wj; }
        if (tid == wi) rowUsed = true;
        colUsed |= 1u << wj;
        if (!rowUsed && bestj == wj) {   // rescan own register row
            float bv = INFINITY; int bj = 0;
#pragma unroll
            for (int j = 0; j < M_GT; ++j) {
                float c = ((colUsed >> j) & 1) ? INFINITY : cr[j];
                if (c < bv) { bv = c; bj = j; }
            }
            bestv = bv; bestj = bj;
        }
        __syncthreads();   // wkey readers done before next iter's write
    }

    if (tid < M_GT) {
        pis[b * M_GT + tid] = my_pi;
        gjs[b * M_GT + tid] = my_gj;
    }

    // bbox loss over matched pairs (threads 0..31, wave 0)
    float l1sum = 0.f, gsum = 0.f;
    if (tid < M_GT) {
        float4 mp = pbS[my_pi];
        float4 mg = gbS[my_gj];
        l1sum = fabsf(mp.x - mg.x) + fabsf(mp.y - mg.y) +
                fabsf(mp.z - mg.z) + fabsf(mp.w - mg.w);
        gsum = 1.f - giou_f(mp, mg);
    }
    // objectness BCE: each thread contributes its own row
    float osum = fmaxf(po, 0.f) - po * (rowUsed ? 1.f : 0.f) +
                 log1pf(__expf(-fabsf(po)));
    for (int off = 32; off > 0; off >>= 1) {
        l1sum += __shfl_xor(l1sum, off);
        gsum  += __shfl_xor(gsum,  off);
        osum  += __shfl_xor(osum,  off);
    }
    if (ln == 0) wosum[wv] = osum;
    __syncthreads();
    if (tid == 0) {
        float l1_loss   = l1sum / 128.f;                       // mean over (32,4)
        float giou_loss = fminf(fmaxf(gsum / 32.f, 0.f), 2.f); // clip [0,2]
        bbox_out[b] = fmaxf(l1_loss + giou_loss, 0.f);
        float ot = wosum[0] + wosum[1] + wosum[2] + wosum[3];
        obj_out[b]  = fmaxf(ot / 256.f, 0.f);
    }
}

// ===== caption: same grid as R4 (row halves), new internals =====
// One block per (row r, half h): bid = r*2+h, r = b*480 + k*15 + p.
// Partial online softmax over 16000 contiguous floats (64 KB).
// Two independent (m,s) chains per thread (stride 512) for load/exp ILP;
// reduce: intra-wave __shfl_xor merge (no barriers) + 4-entry LDS combine
// (1 barrier total, was 9).
__global__ __launch_bounds__(256) void caption_lse_kernel(
    const float* __restrict__ cl, const int* __restrict__ gt_tokens,
    const int* __restrict__ pis, const int* __restrict__ gjs,
    float* __restrict__ pm, float* __restrict__ ps, float* __restrict__ tl)
{
    const int bid = blockIdx.x;
    const int h   = bid & 1;
    const int r   = bid >> 1;
    const int b   = r / (M_GT * P_POS);
    const int rem = r % (M_GT * P_POS);
    const int k   = rem / P_POS;
    const int p   = rem % P_POS;
    const int tid = threadIdx.x;
    const int wv  = tid >> 6;
    const int ln  = tid & 63;

    const int n = pis[b * M_GT + k];
    const float* row = cl + ((size_t)(b * N_PRED + n) * L_TOK + p) * V_VOCAB;
    const float4* row4 = (const float4*)row;

    const int base = h * HALF4;
    const int end  = base + HALF4;
    float m0 = -INFINITY, s0 = 0.f;
    float m1 = -INFINITY, s1 = 0.f;
    for (int idx = base + tid; idx < end; idx += 512) {
        {
            float4 v = row4[idx];
            float m4 = fmaxf(fmaxf(v.x, v.y), fmaxf(v.z, v.w));
            float mn = fmaxf(m0, m4);
            s0 = s0 * __expf(m0 - mn) +
                 __expf(v.x - mn) + __expf(v.y - mn) +
                 __expf(v.z - mn) + __expf(v.w - mn);
            m0 = mn;
        }
        int i2 = idx + 256;
        if (i2 < end) {
            float4 v = row4[i2];
            float m4 = fmaxf(fmaxf(v.x, v.y), fmaxf(v.z, v.w));
            float mn = fmaxf(m1, m4);
            s1 = s1 * __expf(m1 - mn) +
                 __expf(v.x - mn) + __expf(v.y - mn) +
                 __expf(v.z - mn) + __expf(v.w - mn);
            m1 = mn;
        }
    }
    // merge the two chains
    float m = fmaxf(m0, m1);
    float s = s0 * __expf(m0 - m) + s1 * __expf(m1 - m);

    // intra-wave (m,s) merge — no barriers
    for (int off = 32; off > 0; off >>= 1) {
        float mo = __shfl_xor(m, off);
        float so = __shfl_xor(s, off);
        float mm = fmaxf(m, mo);
        s = s * __expf(m - mm) + so * __expf(mo - mm);
        m = mm;
    }

    __shared__ float wm[4], wsum[4];
    if (ln == 0) { wm[wv] = m; wsum[wv] = s; }
    __syncthreads();
    if (tid == 0) {
        float mm = fmaxf(fmaxf(wm[0], wm[1]), fmaxf(wm[2], wm[3]));
        float st = wsum[0] * __expf(wm[0] - mm) + wsum[1] * __expf(wm[1] - mm) +
                   wsum[2] * __expf(wm[2] - mm) + wsum[3] * __expf(wm[3] - mm);
        pm[bid] = mm;
        ps[bid] = st;
        if (h == 0) {
            const int gj  = gjs[b * M_GT + k];
            const int tgt = gt_tokens[(b * M_GT + gj) * L_TOK + (p + 1)];
            tl[r] = row[tgt];
        }
    }
}

// ===== R4-proven finalize (unchanged): merge halves, CE means, weights =====
__global__ __launch_bounds__(64) void finalize_kernel(
    const float* __restrict__ pm, const float* __restrict__ ps,
    const float* __restrict__ tl,
    const float* __restrict__ bbox, const float* __restrict__ obj,
    float* __restrict__ out)
{
    const int l = threadIdx.x;      // l = b*32 + k
    float sum = 0.f;
#pragma unroll
    for (int p = 0; p < P_POS; ++p) {
        int r = l * P_POS + p;
        float m0 = pm[2*r],   s0 = ps[2*r];
        float m1 = pm[2*r+1], s1 = ps[2*r+1];
        float mm = fmaxf(m0, m1);
        float s  = s0 * __expf(m0 - mm) + s1 * __expf(m1 - mm);
        sum += mm + __logf(s) - tl[r];
    }
    float cek = fmaxf(sum / (float)P_POS, 0.f);   // clip(ce,0) per match
    for (int off = 16; off > 0; off >>= 1) cek += __shfl_xor(cek, off);
    float cap_b = fmaxf(cek / (float)M_GT, 0.f);  // clip(mean,0) per sample
    float cap0 = __shfl(cap_b, 0);
    float cap1 = __shfl(cap_b, 32);
    if (l == 0) {
        float bb0 = bbox[0], bb1 = bbox[1];
        float ob0 = obj[0],  ob1 = obj[1];
        float per0 = 5.f * bb0 + 0.1f * cap0 + ob0;
        float per1 = 5.f * bb1 + 0.1f * cap1 + ob1;
        out[0] = fmaxf(0.5f * (per0 + per1), 0.f);
        out[1] = 5.f  * 0.5f * (bb0 + bb1);
        out[2] = 0.1f * 0.5f * (cap0 + cap1);
        out[3] = 0.5f * (ob0 + ob1);
    }
}

extern "C" void kernel_launch(void* const* d_in, const int* in_sizes, int n_in,
                              void* d_out, int out_size, void* d_ws, size_t ws_size,
                              hipStream_t stream) {
    const float* pred_boxes = (const float*)d_in[0];   // (2,256,4)
    const float* pred_obj   = (const float*)d_in[1];   // (2,256)
    const float* cap_logits = (const float*)d_in[2];   // (2,256,16,32000)
    const float* gt_boxes   = (const float*)d_in[3];   // (2,32,4)
    const int*   gt_tokens  = (const int*)d_in[4];     // (2,32,16) int32
    float* out = (float*)d_out;                        // (4,)

    int*   pis  = (int*)d_ws;                  // 64 ints
    int*   gjs  = pis + B_SZ * M_GT;           // 64 ints
    float* bbox = (float*)(gjs + B_SZ * M_GT); // 2 floats
    float* obj  = bbox + B_SZ;                 // 2 floats
    float* pm   = obj + B_SZ;                  // 1920 floats (960 rows x 2)
    float* ps   = pm + 2 * NROW;               // 1920 floats
    float* tl   = ps + 2 * NROW;               // 960 floats

    match_bbox_obj_kernel<<<B_SZ, 256, 0, stream>>>(
        pred_boxes, pred_obj, gt_boxes, pis, gjs, bbox, obj);
    caption_lse_kernel<<<2 * NROW, 256, 0, stream>>>(
        cap_logits, gt_tokens, pis, gjs, pm, ps, tl);
    finalize_kernel<<<1, 64, 0, stream>>>(pm, ps, tl, bbox, obj, out);
}